// Round 8
// baseline (185.150 us; speedup 1.0000x reference)
//
#include <hip/hip_runtime.h>
#include <hip/hip_cooperative_groups.h>

namespace cg = cooperative_groups;

#define PN 131072
#define PH 1024
#define G 128
#define GPTS (G * G)
#define NBLK 512
#define NTHR 512

// ---- workspace layout (float offsets) ----
// [0..8191]     pk (1024 * 8 floats)
// [8192..8193]  sw2 partials (blocks 0,1)
// [8196]        sw2 final
// [8200..8203]  bnd: ordered-uint keys min0, max0, min1, max1
// [8208..10255] part: uint4[NBLK] (8 KiB)
// [10496..]     grid float4[G*G] (256 KiB; 10496*4 % 16 == 0)

static __device__ __forceinline__ unsigned fkey(float f) {
    unsigned u = __float_as_uint(f);
    return (u & 0x80000000u) ? ~u : (u | 0x80000000u);
}
static __device__ __forceinline__ float funkey(unsigned k) {
    unsigned u = (k & 0x80000000u) ? (k ^ 0x80000000u) : ~k;
    return __uint_as_float(u);
}
// returns {lo0, step0, lo1, step1}
static __device__ __forceinline__ float4 grid_map(const unsigned* __restrict__ bnd) {
    const float mn0 = funkey(bnd[0]), mx0 = funkey(bnd[1]);
    const float mn1 = funkey(bnd[2]), mx1 = funkey(bnd[3]);
    const float pad0 = 1e-4f * (mx0 - mn0) + 1e-6f;
    const float pad1 = 1e-4f * (mx1 - mn1) + 1e-6f;
    const float lo0 = mn0 - pad0, hi0 = mx0 + pad0;
    const float lo1 = mn1 - pad1, hi1 = mx1 + pad1;
    return make_float4(lo0, (hi0 - lo0) * (1.0f / (G - 1)),
                       lo1, (hi1 - lo1) * (1.0f / (G - 1)));
}
// Catmull-Rom weights for t in [0,1)
static __device__ __forceinline__ void cr_w(float t, float w[4]) {
    w[0] = t * (-0.5f + t * (1.0f - 0.5f * t));
    w[1] = 1.0f + t * t * (-2.5f + 1.5f * t);
    w[2] = t * (0.5f + t * (2.0f - 1.5f * t));
    w[3] = t * t * (-0.5f + 0.5f * t);
}

__global__ __launch_bounds__(NTHR, 4) void fused_kernel(const float4* __restrict__ x4,
                                                        const float2* __restrict__ x2,
                                                        const float* __restrict__ W1,
                                                        const float* __restrict__ b1,
                                                        const float* __restrict__ w2,
                                                        const float* __restrict__ b2p,
                                                        float* __restrict__ ws,
                                                        float* __restrict__ out) {
    float* pk          = ws;
    float* sw2part     = ws + 8192;
    float* sw2f        = ws + 8196;
    unsigned* bnd      = (unsigned*)(ws + 8200);
    uint4* part        = (uint4*)(ws + 8208);
    float4* grid       = (float4*)(ws + 10496);
    const float4* pk4  = (const float4*)pk;

    const int bid  = blockIdx.x;
    const int tid  = threadIdx.x;
    const int lane = tid & 63;
    const int wv   = tid >> 6;
    const int gtid = bid * NTHR + tid;

    __shared__ float4 lds[8][32];        // 4 KiB, reused across phases
    __shared__ float sred[8];
    uint4* ldsu = (uint4*)&lds[0][0];

    cg::grid_group gg = cg::this_grid();

    // ================= P0: prep (blocks 0,1) + bounds partials (all) =========
    if (bid < 2) {
        const int h = bid * NTHR + tid;          // 0..1023
        const float SC = 2.8853900817779268f;    // 2*log2(e)
        const float w10 = W1[2 * h], w11 = W1[2 * h + 1], w2h = w2[h];
        float* q = pk + (size_t)h * 8;
        q[0] = w10 * SC;
        q[1] = w11 * SC;
        q[2] = b1[h] * SC;
        q[3] = -2.0f * w2h;
        q[4] = 4.0f * w10 * w2h;
        q[5] = 4.0f * w11 * w2h;
        q[6] = 4.0f * w11 * w11 * w2h;
        q[7] = -8.0f * w11 * w11 * w2h;
        float wsum = w2h;
        #pragma unroll
        for (int m = 32; m >= 1; m >>= 1) wsum += __shfl_xor(wsum, m, 64);
        if (lane == 0) sred[wv] = wsum;
    }

    unsigned mn0 = 0xFFFFFFFFu, mx0 = 0u, mn1 = 0xFFFFFFFFu, mx1 = 0u;
    if (gtid < PN / 2) {                         // 65536 float4 = 131072 float2
        const float4 v = x4[gtid];
        const unsigned ka0 = fkey(v.x), ka1 = fkey(v.y);
        const unsigned kb0 = fkey(v.z), kb1 = fkey(v.w);
        mn0 = min(ka0, kb0); mx0 = max(ka0, kb0);
        mn1 = min(ka1, kb1); mx1 = max(ka1, kb1);
    }
    #pragma unroll
    for (int m = 32; m >= 1; m >>= 1) {
        mn0 = min(mn0, (unsigned)__shfl_xor((int)mn0, m, 64));
        mx0 = max(mx0, (unsigned)__shfl_xor((int)mx0, m, 64));
        mn1 = min(mn1, (unsigned)__shfl_xor((int)mn1, m, 64));
        mx1 = max(mx1, (unsigned)__shfl_xor((int)mx1, m, 64));
    }
    if (lane == 0) ldsu[wv] = make_uint4(mn0, mx0, mn1, mx1);
    __syncthreads();
    if (tid == 0) {
        uint4 a = ldsu[0];
        #pragma unroll
        for (int w = 1; w < 8; ++w) {
            const uint4 o = ldsu[w];
            a.x = min(a.x, o.x); a.y = max(a.y, o.y);
            a.z = min(a.z, o.z); a.w = max(a.w, o.w);
        }
        part[bid] = a;
        if (bid < 2) {
            float s = sred[0];
            #pragma unroll
            for (int w = 1; w < 8; ++w) s += sred[w];
            sw2part[bid] = s;
        }
    }

    gg.sync();

    // ================= P1: block 0 reduces the NBLK partials =================
    if (bid == 0) {
        uint4 a = part[tid];                      // NBLK == NTHR == 512
        #pragma unroll
        for (int m = 32; m >= 1; m >>= 1) {
            a.x = min(a.x, (unsigned)__shfl_xor((int)a.x, m, 64));
            a.y = max(a.y, (unsigned)__shfl_xor((int)a.y, m, 64));
            a.z = min(a.z, (unsigned)__shfl_xor((int)a.z, m, 64));
            a.w = max(a.w, (unsigned)__shfl_xor((int)a.w, m, 64));
        }
        if (lane == 0) ldsu[wv] = a;
        __syncthreads();
        if (tid == 0) {
            uint4 r = ldsu[0];
            #pragma unroll
            for (int w = 1; w < 8; ++w) {
                const uint4 o = ldsu[w];
                r.x = min(r.x, o.x); r.y = max(r.y, o.y);
                r.z = min(r.z, o.z); r.w = max(r.w, o.w);
            }
            bnd[0] = r.x; bnd[1] = r.y; bnd[2] = r.z; bnd[3] = r.w;
            sw2f[0] = sw2part[0] + sw2part[1];
        }
    }

    gg.sync();

    // ================= P2: grid_eval — 32 points/block, 16-way h split =======
    {
        const int c  = wv * 2 + (lane & 1);       // h-chunk 0..15 (64 h each)
        const int p  = bid * 32 + (lane >> 1);    // grid point
        const int ix = p & (G - 1);
        const int iy = p >> 7;

        const float4 mp = grid_map(bnd);
        const float x0 = __builtin_fmaf((float)ix, mp.y, mp.x);
        const float x1 = __builtin_fmaf((float)iy, mp.w, mp.z);

        const float4* __restrict__ pw = pk4 + c * 128;   // 64 h * 2 float4

        float a_r = 0.f, a_u1 = 0.f, a_u2 = 0.f, a_u3 = 0.f, a_u4 = 0.f;

        #pragma unroll 4
        for (int hp = 0; hp < 32; ++hp) {
            const float4 A0 = pw[4 * hp + 0];
            const float4 A1 = pw[4 * hp + 1];
            const float4 B0 = pw[4 * hp + 2];
            const float4 B1 = pw[4 * hp + 3];

            float zsa = __builtin_fmaf(x0, A0.x, __builtin_fmaf(x1, A0.y, A0.z));
            float zsb = __builtin_fmaf(x0, B0.x, __builtin_fmaf(x1, B0.y, B0.z));
            zsa = fminf(zsa, 40.0f);
            zsb = fminf(zsb, 40.0f);
            const float ea = __builtin_amdgcn_exp2f(zsa);
            const float eb = __builtin_amdgcn_exp2f(zsb);
            const float da = ea + 1.0f;
            const float db = eb + 1.0f;
            const float rab = __builtin_amdgcn_rcpf(da * db);
            const float ra = rab * db;
            const float rb = rab * da;
            const float ua = __builtin_fmaf(-ra, ra, ra);
            const float ub = __builtin_fmaf(-rb, rb, rb);
            const float rua = ra * ua;
            const float rub = rb * ub;

            a_r  = __builtin_fmaf(ra,  A0.w, a_r);
            a_r  = __builtin_fmaf(rb,  B0.w, a_r);
            a_u1 = __builtin_fmaf(ua,  A1.x, a_u1);
            a_u1 = __builtin_fmaf(ub,  B1.x, a_u1);
            a_u2 = __builtin_fmaf(ua,  A1.y, a_u2);
            a_u2 = __builtin_fmaf(ub,  B1.y, a_u2);
            a_u3 = __builtin_fmaf(ua,  A1.z, a_u3);
            a_u3 = __builtin_fmaf(ub,  B1.z, a_u3);
            a_u4 = __builtin_fmaf(rua, A1.w, a_u4);
            a_u4 = __builtin_fmaf(rub, B1.w, a_u4);
        }
        float aD = a_u3 + a_u4;

        // combine lane pairs (chunks 2wv, 2wv+1)
        a_r  += __shfl_xor(a_r,  1, 64);
        a_u1 += __shfl_xor(a_u1, 1, 64);
        a_u2 += __shfl_xor(a_u2, 1, 64);
        aD   += __shfl_xor(aD,   1, 64);

        __syncthreads();   // lds free from previous phase use
        if ((lane & 1) == 0) lds[wv][lane >> 1] = make_float4(a_r, a_u1, a_u2, aD);
        __syncthreads();
        if (tid < 32) {
            float4 s = lds[0][tid];
            #pragma unroll
            for (int w = 1; w < 8; ++w) {
                const float4 o = lds[w][tid];
                s.x += o.x; s.y += o.y; s.z += o.z; s.w += o.w;
            }
            const float f   = sw2f[0] + b2p[0] + s.x;
            const float ft  = s.y;
            const float fx  = s.z;
            const float fxx = -2.0f * s.w;
            grid[bid * 32 + tid] = make_float4(f, ft, fx, fxx);
        }
    }

    gg.sync();

    // ================= P3: interp — 2 threads per row ========================
    {
        const int row = gtid >> 1;                 // 0..131071, balanced
        const int half = gtid & 1;                 // stencil rows {0,1} or {2,3}
        const float2 xv = x2[row];
        const float4 mp = grid_map(bnd);
        const float inv0 = __builtin_amdgcn_rcpf(mp.y);
        const float inv1 = __builtin_amdgcn_rcpf(mp.w);

        float u = (xv.x - mp.x) * inv0;
        float v = (xv.y - mp.z) * inv1;
        u = fminf(fmaxf(u, 0.0f), (float)(G - 1) - 1e-3f);
        v = fminf(fmaxf(v, 0.0f), (float)(G - 1) - 1e-3f);
        int iu = (int)u;  iu = iu > G - 2 ? G - 2 : iu;
        int iv = (int)v;  iv = iv > G - 2 ? G - 2 : iv;
        const float fu = u - (float)iu;
        const float fv = v - (float)iv;

        float wu[4], wv_[4];
        cr_w(fu, wu);
        cr_w(fv, wv_);

        const int ju0 = iu - 1 < 0 ? 0 : iu - 1;
        const int ju3 = iu + 2 > G - 1 ? G - 1 : iu + 2;
        const int jv0 = iv - 1 < 0 ? 0 : iv - 1;
        const int jv3 = iv + 2 > G - 1 ? G - 1 : iv + 2;
        const int rowsIdx[4] = { jv0 * G, iv * G, (iv + 1) * G, jv3 * G };

        float af = 0.f, at = 0.f, ax = 0.f, axx = 0.f;
        #pragma unroll
        for (int rr = 0; rr < 2; ++rr) {
            const int r = 2 * half + rr;
            const int base = rowsIdx[r];
            const float4 g0 = grid[base + ju0];
            const float4 g1 = grid[base + iu];
            const float4 g2 = grid[base + iu + 1];
            const float4 g3 = grid[base + ju3];
            const float rf  = wu[0] * g0.x + wu[1] * g1.x + wu[2] * g2.x + wu[3] * g3.x;
            const float rt  = wu[0] * g0.y + wu[1] * g1.y + wu[2] * g2.y + wu[3] * g3.y;
            const float rx  = wu[0] * g0.z + wu[1] * g1.z + wu[2] * g2.z + wu[3] * g3.z;
            const float rxx = wu[0] * g0.w + wu[1] * g1.w + wu[2] * g2.w + wu[3] * g3.w;
            af  = __builtin_fmaf(wv_[r], rf,  af);
            at  = __builtin_fmaf(wv_[r], rt,  at);
            ax  = __builtin_fmaf(wv_[r], rx,  ax);
            axx = __builtin_fmaf(wv_[r], rxx, axx);
        }
        af  += __shfl_xor(af,  1, 64);
        at  += __shfl_xor(at,  1, 64);
        ax  += __shfl_xor(ax,  1, 64);
        axx += __shfl_xor(axx, 1, 64);

        if (half == 0) {
            const float x1 = xv.y;
            const float pde = __builtin_fmaf(0.5f * x1, x1, at)
                            + 0.5f * axx
                            + 0.5f * x1 * ax
                            - 0.069444444444444445f * ax * ax;
            out[row] = af;
            out[PN + row] = pde;
        }
    }
}

extern "C" void kernel_launch(void* const* d_in, const int* in_sizes, int n_in,
                              void* d_out, int out_size, void* d_ws, size_t ws_size,
                              hipStream_t stream) {
    const float4* x4 = (const float4*)d_in[0];
    const float2* x2 = (const float2*)d_in[0];
    const float* W1  = (const float*)d_in[1];
    const float* b1  = (const float*)d_in[2];
    const float* w2  = (const float*)d_in[3];
    const float* b2  = (const float*)d_in[4];
    float* ws  = (float*)d_ws;
    float* out = (float*)d_out;

    void* args[] = { &x4, &x2, &W1, &b1, &w2, &b2, &ws, &out };
    hipLaunchCooperativeKernel((const void*)fused_kernel, dim3(NBLK), dim3(NTHR),
                               args, 0, stream);
}

// Round 9
// 45.788 us; speedup vs baseline: 4.0436x; 4.0436x over previous
//
#include <hip/hip_runtime.h>

#define PN 131072
#define PH 1024
#define G 128
#define GPTS (G * G)
#define NBA 128             // kernel A blocks

// ---- workspace layout (float offsets) ----
// [0..8191]    pk (1024 * 8 floats)
// [8192..8195] sw2part (4 floats, one per prep block)
// [8196..8199] mp (float4 published by grid_eval block 0)
// [8208..8719] part: uint4[NBA]
// [8960..]     grid float4[G*G] (256 KiB)

static __device__ __forceinline__ unsigned fkey(float f) {
    unsigned u = __float_as_uint(f);
    return (u & 0x80000000u) ? ~u : (u | 0x80000000u);
}
static __device__ __forceinline__ float funkey(unsigned k) {
    unsigned u = (k & 0x80000000u) ? (k ^ 0x80000000u) : ~k;
    return __uint_as_float(u);
}
// {lo0, step0, lo1, step1} from reduced ordered-uint bounds
static __device__ __forceinline__ float4 grid_map_u(uint4 r) {
    const float mn0 = funkey(r.x), mx0 = funkey(r.y);
    const float mn1 = funkey(r.z), mx1 = funkey(r.w);
    const float pad0 = 1e-4f * (mx0 - mn0) + 1e-6f;
    const float pad1 = 1e-4f * (mx1 - mn1) + 1e-6f;
    const float lo0 = mn0 - pad0, hi0 = mx0 + pad0;
    const float lo1 = mn1 - pad1, hi1 = mx1 + pad1;
    return make_float4(lo0, (hi0 - lo0) * (1.0f / (G - 1)),
                       lo1, (hi1 - lo1) * (1.0f / (G - 1)));
}
// Catmull-Rom weights for t in [0,1)
static __device__ __forceinline__ void cr_w(float t, float w[4]) {
    w[0] = t * (-0.5f + t * (1.0f - 0.5f * t));
    w[1] = 1.0f + t * t * (-2.5f + 1.5f * t);
    w[2] = t * (0.5f + t * (2.0f - 1.5f * t));
    w[3] = t * t * (-0.5f + 0.5f * t);
}

// ===== Kernel A: bounds partials (all blocks) + prep (blocks 0..3) =====
__global__ __launch_bounds__(256) void prep_bounds_kernel(const float4* __restrict__ x4,
                                                          const float* __restrict__ W1,
                                                          const float* __restrict__ b1,
                                                          const float* __restrict__ w2,
                                                          float* __restrict__ pk,
                                                          float* __restrict__ sw2part,
                                                          uint4* __restrict__ part) {
    const int bid = blockIdx.x, tid = threadIdx.x;
    const int lane = tid & 63, wv = tid >> 6;
    __shared__ uint4 ldsu[4];
    __shared__ float sred[4];

    // bounds over x: 65536 float4 total, 32768 threads -> 2 each
    unsigned mn0 = 0xFFFFFFFFu, mx0 = 0u, mn1 = 0xFFFFFFFFu, mx1 = 0u;
    #pragma unroll
    for (int k = 0; k < 2; ++k) {
        const float4 v = x4[bid * 256 + tid + k * (NBA * 256)];
        const unsigned ka0 = fkey(v.x), ka1 = fkey(v.y);
        const unsigned kb0 = fkey(v.z), kb1 = fkey(v.w);
        mn0 = min(mn0, min(ka0, kb0));
        mx0 = max(mx0, max(ka0, kb0));
        mn1 = min(mn1, min(ka1, kb1));
        mx1 = max(mx1, max(ka1, kb1));
    }
    #pragma unroll
    for (int m = 32; m >= 1; m >>= 1) {
        mn0 = min(mn0, (unsigned)__shfl_xor((int)mn0, m, 64));
        mx0 = max(mx0, (unsigned)__shfl_xor((int)mx0, m, 64));
        mn1 = min(mn1, (unsigned)__shfl_xor((int)mn1, m, 64));
        mx1 = max(mx1, (unsigned)__shfl_xor((int)mx1, m, 64));
    }
    if (lane == 0) ldsu[wv] = make_uint4(mn0, mx0, mn1, mx1);
    __syncthreads();
    if (tid == 0) {
        uint4 a = ldsu[0];
        #pragma unroll
        for (int w = 1; w < 4; ++w) {
            const uint4 o = ldsu[w];
            a.x = min(a.x, o.x); a.y = max(a.y, o.y);
            a.z = min(a.z, o.z); a.w = max(a.w, o.w);
        }
        part[bid] = a;
    }

    // prep: blocks 0..3 cover h = 0..1023
    if (bid < 4) {
        const int h = bid * 256 + tid;
        const float SC = 2.8853900817779268f;   // 2*log2(e)
        const float w10 = W1[2 * h], w11 = W1[2 * h + 1], w2h = w2[h];
        float* q = pk + (size_t)h * 8;
        q[0] = w10 * SC;
        q[1] = w11 * SC;
        q[2] = b1[h] * SC;
        q[3] = -2.0f * w2h;
        q[4] = 4.0f * w10 * w2h;
        q[5] = 4.0f * w11 * w2h;
        q[6] = 4.0f * w11 * w11 * w2h;
        q[7] = -8.0f * w11 * w11 * w2h;
        float wsum = w2h;
        #pragma unroll
        for (int m = 32; m >= 1; m >>= 1) wsum += __shfl_xor(wsum, m, 64);
        if (lane == 0) sred[wv] = wsum;
        __syncthreads();
        if (tid == 0) sw2part[bid] = sred[0] + sred[1] + sred[2] + sred[3];
    }
}

// ===== Kernel B: inline bounds finalize + grid_eval (32 pts/block, 16-way h) =====
__global__ __launch_bounds__(512) void grid_eval_kernel(const float4* __restrict__ pk4,
                                                        const float* __restrict__ sw2part,
                                                        const float* __restrict__ b2p,
                                                        const uint4* __restrict__ part,
                                                        float4* __restrict__ mpout,
                                                        float4* __restrict__ gridout) {
    const int bid = blockIdx.x, tid = threadIdx.x;
    const int lane = tid & 63, wv = tid >> 6;

    __shared__ float4 lds[8][32];
    __shared__ uint4 bred[2];
    __shared__ float4 smp;
    __shared__ float sfb;

    // finalize bounds from NBA partials (2 waves)
    if (tid < NBA) {
        uint4 a = part[tid];
        #pragma unroll
        for (int m = 32; m >= 1; m >>= 1) {
            a.x = min(a.x, (unsigned)__shfl_xor((int)a.x, m, 64));
            a.y = max(a.y, (unsigned)__shfl_xor((int)a.y, m, 64));
            a.z = min(a.z, (unsigned)__shfl_xor((int)a.z, m, 64));
            a.w = max(a.w, (unsigned)__shfl_xor((int)a.w, m, 64));
        }
        if (lane == 0) bred[wv] = a;
    }
    __syncthreads();
    if (tid == 0) {
        uint4 r = bred[0];
        const uint4 o = bred[1];
        r.x = min(r.x, o.x); r.y = max(r.y, o.y);
        r.z = min(r.z, o.z); r.w = max(r.w, o.w);
        const float4 mp = grid_map_u(r);
        smp = mp;
        sfb = sw2part[0] + sw2part[1] + sw2part[2] + sw2part[3] + b2p[0];
        if (bid == 0) mpout[0] = mp;
    }
    __syncthreads();
    const float4 mp = smp;
    const float fb = sfb;

    const int c  = wv * 2 + (lane & 1);       // h-chunk 0..15 (64 h each)
    const int p  = bid * 32 + (lane >> 1);    // grid point
    const int ix = p & (G - 1);
    const int iy = p >> 7;

    const float x0 = __builtin_fmaf((float)ix, mp.y, mp.x);
    const float x1 = __builtin_fmaf((float)iy, mp.w, mp.z);

    const float4* __restrict__ pw = pk4 + c * 128;   // 64 h * 2 float4

    float a_r = 0.f, a_u1 = 0.f, a_u2 = 0.f, a_u3 = 0.f, a_u4 = 0.f;

    #pragma unroll 4
    for (int hp = 0; hp < 32; ++hp) {
        const float4 A0 = pw[4 * hp + 0];
        const float4 A1 = pw[4 * hp + 1];
        const float4 B0 = pw[4 * hp + 2];
        const float4 B1 = pw[4 * hp + 3];

        float zsa = __builtin_fmaf(x0, A0.x, __builtin_fmaf(x1, A0.y, A0.z));
        float zsb = __builtin_fmaf(x0, B0.x, __builtin_fmaf(x1, B0.y, B0.z));
        zsa = fminf(zsa, 40.0f);
        zsb = fminf(zsb, 40.0f);
        const float ea = __builtin_amdgcn_exp2f(zsa);
        const float eb = __builtin_amdgcn_exp2f(zsb);
        const float da = ea + 1.0f;
        const float db = eb + 1.0f;
        const float rab = __builtin_amdgcn_rcpf(da * db);
        const float ra = rab * db;
        const float rb = rab * da;
        const float ua = __builtin_fmaf(-ra, ra, ra);
        const float ub = __builtin_fmaf(-rb, rb, rb);
        const float rua = ra * ua;
        const float rub = rb * ub;

        a_r  = __builtin_fmaf(ra,  A0.w, a_r);
        a_r  = __builtin_fmaf(rb,  B0.w, a_r);
        a_u1 = __builtin_fmaf(ua,  A1.x, a_u1);
        a_u1 = __builtin_fmaf(ub,  B1.x, a_u1);
        a_u2 = __builtin_fmaf(ua,  A1.y, a_u2);
        a_u2 = __builtin_fmaf(ub,  B1.y, a_u2);
        a_u3 = __builtin_fmaf(ua,  A1.z, a_u3);
        a_u3 = __builtin_fmaf(ub,  B1.z, a_u3);
        a_u4 = __builtin_fmaf(rua, A1.w, a_u4);
        a_u4 = __builtin_fmaf(rub, B1.w, a_u4);
    }
    float aD = a_u3 + a_u4;

    // combine lane pairs (chunks 2wv, 2wv+1)
    a_r  += __shfl_xor(a_r,  1, 64);
    a_u1 += __shfl_xor(a_u1, 1, 64);
    a_u2 += __shfl_xor(a_u2, 1, 64);
    aD   += __shfl_xor(aD,   1, 64);

    if ((lane & 1) == 0) lds[wv][lane >> 1] = make_float4(a_r, a_u1, a_u2, aD);
    __syncthreads();
    if (tid < 32) {
        float4 s = lds[0][tid];
        #pragma unroll
        for (int w = 1; w < 8; ++w) {
            const float4 o = lds[w][tid];
            s.x += o.x; s.y += o.y; s.z += o.z; s.w += o.w;
        }
        const float f   = fb + s.x;
        const float ft  = s.y;
        const float fx  = s.z;
        const float fxx = -2.0f * s.w;
        gridout[bid * 32 + tid] = make_float4(f, ft, fx, fxx);
    }
}

// ===== Kernel C: bicubic interpolation, 1 row/thread =====
__global__ __launch_bounds__(256) void interp_kernel(const float2* __restrict__ x2,
                                                     const float4* __restrict__ mpp,
                                                     const float4* __restrict__ grid,
                                                     float* __restrict__ out) {
    const int i = blockIdx.x * 256 + threadIdx.x;
    const float2 xv = x2[i];
    const float4 mp = mpp[0];
    const float inv0 = __builtin_amdgcn_rcpf(mp.y);
    const float inv1 = __builtin_amdgcn_rcpf(mp.w);

    float u = (xv.x - mp.x) * inv0;
    float v = (xv.y - mp.z) * inv1;
    u = fminf(fmaxf(u, 0.0f), (float)(G - 1) - 1e-3f);
    v = fminf(fmaxf(v, 0.0f), (float)(G - 1) - 1e-3f);
    int iu = (int)u;  iu = iu > G - 2 ? G - 2 : iu;
    int iv = (int)v;  iv = iv > G - 2 ? G - 2 : iv;
    const float fu = u - (float)iu;
    const float fv = v - (float)iv;

    float wu[4], wv_[4];
    cr_w(fu, wu);
    cr_w(fv, wv_);

    const int ju0 = iu - 1 < 0 ? 0 : iu - 1;
    const int ju3 = iu + 2 > G - 1 ? G - 1 : iu + 2;
    const int jv0 = iv - 1 < 0 ? 0 : iv - 1;
    const int jv3 = iv + 2 > G - 1 ? G - 1 : iv + 2;
    const int rows[4] = { jv0 * G, iv * G, (iv + 1) * G, jv3 * G };

    float af = 0.f, at = 0.f, ax = 0.f, axx = 0.f;
    #pragma unroll
    for (int r = 0; r < 4; ++r) {
        const int base = rows[r];
        const float4 g0 = grid[base + ju0];
        const float4 g1 = grid[base + iu];
        const float4 g2 = grid[base + iu + 1];
        const float4 g3 = grid[base + ju3];
        const float rf  = wu[0] * g0.x + wu[1] * g1.x + wu[2] * g2.x + wu[3] * g3.x;
        const float rt  = wu[0] * g0.y + wu[1] * g1.y + wu[2] * g2.y + wu[3] * g3.y;
        const float rx  = wu[0] * g0.z + wu[1] * g1.z + wu[2] * g2.z + wu[3] * g3.z;
        const float rxx = wu[0] * g0.w + wu[1] * g1.w + wu[2] * g2.w + wu[3] * g3.w;
        af  = __builtin_fmaf(wv_[r], rf,  af);
        at  = __builtin_fmaf(wv_[r], rt,  at);
        ax  = __builtin_fmaf(wv_[r], rx,  ax);
        axx = __builtin_fmaf(wv_[r], rxx, axx);
    }

    const float x1 = xv.y;
    const float pde = __builtin_fmaf(0.5f * x1, x1, at)
                    + 0.5f * axx
                    + 0.5f * x1 * ax
                    - 0.069444444444444445f * ax * ax;
    out[i] = af;
    out[PN + i] = pde;
}

extern "C" void kernel_launch(void* const* d_in, const int* in_sizes, int n_in,
                              void* d_out, int out_size, void* d_ws, size_t ws_size,
                              hipStream_t stream) {
    const float* x  = (const float*)d_in[0];
    const float* W1 = (const float*)d_in[1];
    const float* b1 = (const float*)d_in[2];
    const float* w2 = (const float*)d_in[3];
    const float* b2 = (const float*)d_in[4];
    float* out = (float*)d_out;

    float* pk      = (float*)d_ws;                    // 8192 floats
    float* sw2part = pk + 8192;                       // 4 floats
    float4* mpout  = (float4*)(pk + 8196);            // 1 float4
    uint4* part    = (uint4*)(pk + 8208);             // NBA uint4
    float4* grid   = (float4*)(pk + 8960);            // G*G float4 = 256 KiB

    prep_bounds_kernel<<<NBA, 256, 0, stream>>>((const float4*)x, W1, b1, w2,
                                                pk, sw2part, part);
    grid_eval_kernel<<<GPTS / 32, 512, 0, stream>>>((const float4*)pk, sw2part, b2,
                                                    part, mpout, grid);
    interp_kernel<<<PN / 256, 256, 0, stream>>>((const float2*)x, mpout, grid, out);
}

// Round 10
// 25.125 us; speedup vs baseline: 7.3691x; 1.8224x over previous
//
#include <hip/hip_runtime.h>

#define PN 131072
#define PH 1024
#define G 128
#define GPTS (G * G)
#define NBA 128             // kernel A blocks

// ---- workspace layout (float offsets) ----
// [0..8191]    pk (1024 * 8 floats)
// [8192..8195] sw2part (4 floats)
// [8196..8199] mp (float4 published by grid_eval block 0)
// [8208..8719] part: uint4[NBA]
// [8960..]     grid float4[G*G] (256 KiB)

static __device__ __forceinline__ unsigned fkey(float f) {
    unsigned u = __float_as_uint(f);
    return (u & 0x80000000u) ? ~u : (u | 0x80000000u);
}
static __device__ __forceinline__ float funkey(unsigned k) {
    unsigned u = (k & 0x80000000u) ? (k ^ 0x80000000u) : ~k;
    return __uint_as_float(u);
}
// {lo0, step0, lo1, step1} from reduced ordered-uint bounds
static __device__ __forceinline__ float4 grid_map_u(uint4 r) {
    const float mn0 = funkey(r.x), mx0 = funkey(r.y);
    const float mn1 = funkey(r.z), mx1 = funkey(r.w);
    const float pad0 = 1e-4f * (mx0 - mn0) + 1e-6f;
    const float pad1 = 1e-4f * (mx1 - mn1) + 1e-6f;
    const float lo0 = mn0 - pad0, hi0 = mx0 + pad0;
    const float lo1 = mn1 - pad1, hi1 = mx1 + pad1;
    return make_float4(lo0, (hi0 - lo0) * (1.0f / (G - 1)),
                       lo1, (hi1 - lo1) * (1.0f / (G - 1)));
}
// Catmull-Rom weights for t in [0,1)
static __device__ __forceinline__ void cr_w(float t, float w[4]) {
    w[0] = t * (-0.5f + t * (1.0f - 0.5f * t));
    w[1] = 1.0f + t * t * (-2.5f + 1.5f * t);
    w[2] = t * (0.5f + t * (2.0f - 1.5f * t));
    w[3] = t * t * (-0.5f + 0.5f * t);
}

// ===== Kernel A: bounds partials (all blocks) + prep (blocks 0..3) =====
__global__ __launch_bounds__(256) void prep_bounds_kernel(const float4* __restrict__ x4,
                                                          const float* __restrict__ W1,
                                                          const float* __restrict__ b1,
                                                          const float* __restrict__ w2,
                                                          float* __restrict__ pk,
                                                          float* __restrict__ sw2part,
                                                          uint4* __restrict__ part) {
    const int bid = blockIdx.x, tid = threadIdx.x;
    const int lane = tid & 63, wv = tid >> 6;
    __shared__ uint4 ldsu[4];
    __shared__ float sred[4];

    // bounds over x: 65536 float4 total, 32768 threads -> 2 each
    unsigned mn0 = 0xFFFFFFFFu, mx0 = 0u, mn1 = 0xFFFFFFFFu, mx1 = 0u;
    #pragma unroll
    for (int k = 0; k < 2; ++k) {
        const float4 v = x4[bid * 256 + tid + k * (NBA * 256)];
        const unsigned ka0 = fkey(v.x), ka1 = fkey(v.y);
        const unsigned kb0 = fkey(v.z), kb1 = fkey(v.w);
        mn0 = min(mn0, min(ka0, kb0));
        mx0 = max(mx0, max(ka0, kb0));
        mn1 = min(mn1, min(ka1, kb1));
        mx1 = max(mx1, max(ka1, kb1));
    }
    #pragma unroll
    for (int m = 32; m >= 1; m >>= 1) {
        mn0 = min(mn0, (unsigned)__shfl_xor((int)mn0, m, 64));
        mx0 = max(mx0, (unsigned)__shfl_xor((int)mx0, m, 64));
        mn1 = min(mn1, (unsigned)__shfl_xor((int)mn1, m, 64));
        mx1 = max(mx1, (unsigned)__shfl_xor((int)mx1, m, 64));
    }
    if (lane == 0) ldsu[wv] = make_uint4(mn0, mx0, mn1, mx1);
    __syncthreads();
    if (tid == 0) {
        uint4 a = ldsu[0];
        #pragma unroll
        for (int w = 1; w < 4; ++w) {
            const uint4 o = ldsu[w];
            a.x = min(a.x, o.x); a.y = max(a.y, o.y);
            a.z = min(a.z, o.z); a.w = max(a.w, o.w);
        }
        part[bid] = a;
    }

    // prep: blocks 0..3 cover h = 0..1023
    if (bid < 4) {
        const int h = bid * 256 + tid;
        const float SC = 2.8853900817779268f;   // 2*log2(e)
        const float w10 = W1[2 * h], w11 = W1[2 * h + 1], w2h = w2[h];
        float* q = pk + (size_t)h * 8;
        q[0] = w10 * SC;
        q[1] = w11 * SC;
        q[2] = b1[h] * SC;
        q[3] = -2.0f * w2h;
        q[4] = 4.0f * w10 * w2h;
        q[5] = 4.0f * w11 * w2h;
        q[6] = 4.0f * w11 * w11 * w2h;
        q[7] = -8.0f * w11 * w11 * w2h;
        float wsum = w2h;
        #pragma unroll
        for (int m = 32; m >= 1; m >>= 1) wsum += __shfl_xor(wsum, m, 64);
        if (lane == 0) sred[wv] = wsum;
        __syncthreads();
        if (tid == 0) sw2part[bid] = sred[0] + sred[1] + sred[2] + sred[3];
    }
}

// ===== Kernel B: inline bounds finalize + grid_eval =====
// 256 blocks x 1024 threads; 64 points/block (lane = point), 16 waves split H
// 16 ways (64 h = 32 pairs per wave). h-chunk is WAVE-UNIFORM -> scalar loads.
__global__ __launch_bounds__(1024) void grid_eval_kernel(const float4* __restrict__ pk4,
                                                         const float* __restrict__ sw2part,
                                                         const float* __restrict__ b2p,
                                                         const uint4* __restrict__ part,
                                                         float4* __restrict__ mpout,
                                                         float4* __restrict__ gridout) {
    const int bid = blockIdx.x, tid = threadIdx.x;
    const int lane = tid & 63, wv = tid >> 6;             // wv 0..15
    const int wvu  = __builtin_amdgcn_readfirstlane(wv);

    __shared__ float4 lds[16][64];   // 16 KiB
    __shared__ uint4 bred[2];
    __shared__ float4 smp;
    __shared__ float sfb;

    // finalize bounds from NBA=128 partials (2 waves)
    if (tid < NBA) {
        uint4 a = part[tid];
        #pragma unroll
        for (int m = 32; m >= 1; m >>= 1) {
            a.x = min(a.x, (unsigned)__shfl_xor((int)a.x, m, 64));
            a.y = max(a.y, (unsigned)__shfl_xor((int)a.y, m, 64));
            a.z = min(a.z, (unsigned)__shfl_xor((int)a.z, m, 64));
            a.w = max(a.w, (unsigned)__shfl_xor((int)a.w, m, 64));
        }
        if (lane == 0) bred[wv] = a;
    }
    __syncthreads();
    if (tid == 0) {
        uint4 r = bred[0];
        const uint4 o = bred[1];
        r.x = min(r.x, o.x); r.y = max(r.y, o.y);
        r.z = min(r.z, o.z); r.w = max(r.w, o.w);
        const float4 mp = grid_map_u(r);
        smp = mp;
        sfb = sw2part[0] + sw2part[1] + sw2part[2] + sw2part[3] + b2p[0];
        if (bid == 0) mpout[0] = mp;
    }
    __syncthreads();
    const float4 mp = smp;
    const float fb = sfb;

    const int p  = bid * 64 + lane;           // grid point (lane = point)
    const int ix = p & (G - 1);
    const int iy = p >> 7;

    const float x0 = __builtin_fmaf((float)ix, mp.y, mp.x);
    const float x1 = __builtin_fmaf((float)iy, mp.w, mp.z);

    const float4* __restrict__ pw = pk4 + (size_t)wvu * 128;   // 64 h * 2 float4

    float a_r = 0.f, a_u1 = 0.f, a_u2 = 0.f, a_u3 = 0.f, a_u4 = 0.f;

    #pragma unroll 4
    for (int hp = 0; hp < 32; ++hp) {
        const float4 A0 = pw[4 * hp + 0];
        const float4 A1 = pw[4 * hp + 1];
        const float4 B0 = pw[4 * hp + 2];
        const float4 B1 = pw[4 * hp + 3];

        float zsa = __builtin_fmaf(x0, A0.x, __builtin_fmaf(x1, A0.y, A0.z));
        float zsb = __builtin_fmaf(x0, B0.x, __builtin_fmaf(x1, B0.y, B0.z));
        zsa = fminf(zsa, 40.0f);
        zsb = fminf(zsb, 40.0f);
        const float ea = __builtin_amdgcn_exp2f(zsa);
        const float eb = __builtin_amdgcn_exp2f(zsb);
        const float da = ea + 1.0f;
        const float db = eb + 1.0f;
        const float rab = __builtin_amdgcn_rcpf(da * db);
        const float ra = rab * db;
        const float rb = rab * da;
        const float ua = __builtin_fmaf(-ra, ra, ra);
        const float ub = __builtin_fmaf(-rb, rb, rb);
        const float rua = ra * ua;
        const float rub = rb * ub;

        a_r  = __builtin_fmaf(ra,  A0.w, a_r);
        a_r  = __builtin_fmaf(rb,  B0.w, a_r);
        a_u1 = __builtin_fmaf(ua,  A1.x, a_u1);
        a_u1 = __builtin_fmaf(ub,  B1.x, a_u1);
        a_u2 = __builtin_fmaf(ua,  A1.y, a_u2);
        a_u2 = __builtin_fmaf(ub,  B1.y, a_u2);
        a_u3 = __builtin_fmaf(ua,  A1.z, a_u3);
        a_u3 = __builtin_fmaf(ub,  B1.z, a_u3);
        a_u4 = __builtin_fmaf(rua, A1.w, a_u4);
        a_u4 = __builtin_fmaf(rub, B1.w, a_u4);
    }
    const float aD = a_u3 + a_u4;

    lds[wv][lane] = make_float4(a_r, a_u1, a_u2, aD);
    __syncthreads();
    if (tid < 64) {
        float4 s = lds[0][tid];
        #pragma unroll
        for (int w = 1; w < 16; ++w) {
            const float4 o = lds[w][tid];
            s.x += o.x; s.y += o.y; s.z += o.z; s.w += o.w;
        }
        const float f   = fb + s.x;
        const float ft  = s.y;
        const float fx  = s.z;
        const float fxx = -2.0f * s.w;
        gridout[bid * 64 + tid] = make_float4(f, ft, fx, fxx);
    }
}

// ===== Kernel C: bicubic interpolation, 1 row/thread =====
__global__ __launch_bounds__(256) void interp_kernel(const float2* __restrict__ x2,
                                                     const float4* __restrict__ mpp,
                                                     const float4* __restrict__ grid,
                                                     float* __restrict__ out) {
    const int i = blockIdx.x * 256 + threadIdx.x;
    const float2 xv = x2[i];
    const float4 mp = mpp[0];
    const float inv0 = __builtin_amdgcn_rcpf(mp.y);
    const float inv1 = __builtin_amdgcn_rcpf(mp.w);

    float u = (xv.x - mp.x) * inv0;
    float v = (xv.y - mp.z) * inv1;
    u = fminf(fmaxf(u, 0.0f), (float)(G - 1) - 1e-3f);
    v = fminf(fmaxf(v, 0.0f), (float)(G - 1) - 1e-3f);
    int iu = (int)u;  iu = iu > G - 2 ? G - 2 : iu;
    int iv = (int)v;  iv = iv > G - 2 ? G - 2 : iv;
    const float fu = u - (float)iu;
    const float fv = v - (float)iv;

    float wu[4], wv_[4];
    cr_w(fu, wu);
    cr_w(fv, wv_);

    const int ju0 = iu - 1 < 0 ? 0 : iu - 1;
    const int ju3 = iu + 2 > G - 1 ? G - 1 : iu + 2;
    const int jv0 = iv - 1 < 0 ? 0 : iv - 1;
    const int jv3 = iv + 2 > G - 1 ? G - 1 : iv + 2;
    const int rows[4] = { jv0 * G, iv * G, (iv + 1) * G, jv3 * G };

    float af = 0.f, at = 0.f, ax = 0.f, axx = 0.f;
    #pragma unroll
    for (int r = 0; r < 4; ++r) {
        const int base = rows[r];
        const float4 g0 = grid[base + ju0];
        const float4 g1 = grid[base + iu];
        const float4 g2 = grid[base + iu + 1];
        const float4 g3 = grid[base + ju3];
        const float rf  = wu[0] * g0.x + wu[1] * g1.x + wu[2] * g2.x + wu[3] * g3.x;
        const float rt  = wu[0] * g0.y + wu[1] * g1.y + wu[2] * g2.y + wu[3] * g3.y;
        const float rx  = wu[0] * g0.z + wu[1] * g1.z + wu[2] * g2.z + wu[3] * g3.z;
        const float rxx = wu[0] * g0.w + wu[1] * g1.w + wu[2] * g2.w + wu[3] * g3.w;
        af  = __builtin_fmaf(wv_[r], rf,  af);
        at  = __builtin_fmaf(wv_[r], rt,  at);
        ax  = __builtin_fmaf(wv_[r], rx,  ax);
        axx = __builtin_fmaf(wv_[r], rxx, axx);
    }

    const float x1 = xv.y;
    const float pde = __builtin_fmaf(0.5f * x1, x1, at)
                    + 0.5f * axx
                    + 0.5f * x1 * ax
                    - 0.069444444444444445f * ax * ax;
    out[i] = af;
    out[PN + i] = pde;
}

extern "C" void kernel_launch(void* const* d_in, const int* in_sizes, int n_in,
                              void* d_out, int out_size, void* d_ws, size_t ws_size,
                              hipStream_t stream) {
    const float* x  = (const float*)d_in[0];
    const float* W1 = (const float*)d_in[1];
    const float* b1 = (const float*)d_in[2];
    const float* w2 = (const float*)d_in[3];
    const float* b2 = (const float*)d_in[4];
    float* out = (float*)d_out;

    float* pk      = (float*)d_ws;                    // 8192 floats
    float* sw2part = pk + 8192;                       // 4 floats
    float4* mpout  = (float4*)(pk + 8196);            // 1 float4
    uint4* part    = (uint4*)(pk + 8208);             // NBA uint4
    float4* grid   = (float4*)(pk + 8960);            // G*G float4 = 256 KiB

    prep_bounds_kernel<<<NBA, 256, 0, stream>>>((const float4*)x, W1, b1, w2,
                                                pk, sw2part, part);
    grid_eval_kernel<<<GPTS / 64, 1024, 0, stream>>>((const float4*)pk, sw2part, b2,
                                                     part, mpout, grid);
    interp_kernel<<<PN / 256, 256, 0, stream>>>((const float2*)x, mpout, grid, out);
}

// Round 11
// 22.008 us; speedup vs baseline: 8.4128x; 1.1416x over previous
//
#include <hip/hip_runtime.h>

#define PN 131072
#define PH 1024
#define G 128
#define GPTS (G * G)
#define GLO   (-5.0f)
#define GSTEP (10.0f / 127.0f)
#define GINV  (127.0f / 10.0f)
#define XMAX  4.9f            // beyond this -> direct-eval fallback

// Catmull-Rom weights for t in [0,1)
static __device__ __forceinline__ void cr_w(float t, float w[4]) {
    w[0] = t * (-0.5f + t * (1.0f - 0.5f * t));
    w[1] = 1.0f + t * t * (-2.5f + 1.5f * t);
    w[2] = t * (0.5f + t * (2.0f - 1.5f * t));
    w[3] = t * t * (-0.5f + 0.5f * t);
}

// ===== K1: grid_eval over fixed range, prep folded into LDS =====
// 256 blocks x 1024 threads. lane = grid point (64/block), 16 waves split H
// into 16 wave-uniform chunks of 64 h (32 pairs). LDS pk read as uniform
// broadcast ds_read_b128.
__global__ __launch_bounds__(1024) void grid_eval_kernel(const float* __restrict__ W1,
                                                         const float* __restrict__ b1,
                                                         const float* __restrict__ w2,
                                                         const float* __restrict__ b2p,
                                                         float4* __restrict__ gridout) {
    __shared__ float4 pkA[PH];        // {SC*w10, SC*w11, SC*b1, w2}
    __shared__ float4 pkB[PH];        // {w10*w2, w11*w2, w11^2*w2, 0}
    __shared__ float4 red[16][64];
    __shared__ float sred[16];
    __shared__ float sfb;

    const int bid = blockIdx.x, tid = threadIdx.x;
    const int lane = tid & 63, wv = tid >> 6;
    const int wvu = __builtin_amdgcn_readfirstlane(wv);
    const float SC = 2.8853900817779268f;   // 2*log2(e)

    // ---- prep: thread t handles h = t ----
    {
        const int h = tid;
        const float w10 = W1[2 * h], w11 = W1[2 * h + 1];
        const float w2h = w2[h], b1h = b1[h];
        const float c2 = w11 * w2h;
        pkA[h] = make_float4(w10 * SC, w11 * SC, b1h * SC, w2h);
        pkB[h] = make_float4(w10 * w2h, c2, w11 * c2, 0.0f);
        float ws = w2h;
        #pragma unroll
        for (int m = 32; m >= 1; m >>= 1) ws += __shfl_xor(ws, m, 64);
        if (lane == 0) sred[wv] = ws;
    }
    __syncthreads();
    if (tid == 0) {
        float s = 0.f;
        #pragma unroll
        for (int w = 0; w < 16; ++w) s += sred[w];
        sfb = s + b2p[0];             // sum(w2) + b2
    }
    __syncthreads();

    const int p  = bid * 64 + lane;
    const int ix = p & (G - 1);
    const int iy = p >> 7;
    const float x0 = __builtin_fmaf((float)ix, GSTEP, GLO);
    const float x1 = __builtin_fmaf((float)iy, GSTEP, GLO);

    const float4* __restrict__ pA = &pkA[wvu * 64];
    const float4* __restrict__ pB = &pkB[wvu * 64];

    float a_r = 0.f, a_u1 = 0.f, a_u2 = 0.f, a_u3 = 0.f, a_u4 = 0.f;

    #pragma unroll 4
    for (int j = 0; j < 32; ++j) {
        const float4 Aa = pA[2 * j];
        const float4 Ab = pA[2 * j + 1];
        const float4 Ba = pB[2 * j];
        const float4 Bb = pB[2 * j + 1];

        float zsa = __builtin_fmaf(x0, Aa.x, __builtin_fmaf(x1, Aa.y, Aa.z));
        float zsb = __builtin_fmaf(x0, Ab.x, __builtin_fmaf(x1, Ab.y, Ab.z));
        zsa = fminf(zsa, 40.0f);
        zsb = fminf(zsb, 40.0f);
        const float ea = __builtin_amdgcn_exp2f(zsa);
        const float eb = __builtin_amdgcn_exp2f(zsb);
        const float da = ea + 1.0f;
        const float db = eb + 1.0f;
        const float rab = __builtin_amdgcn_rcpf(da * db);
        const float ra = rab * db;                       // 1/(1+e^{2za})
        const float rb = rab * da;
        const float ua = __builtin_fmaf(-ra, ra, ra);    // r - r^2
        const float ub = __builtin_fmaf(-rb, rb, rb);
        const float rua = ra * ua;
        const float rub = rb * ub;

        a_r  = __builtin_fmaf(ra,  Aa.w, a_r);
        a_r  = __builtin_fmaf(rb,  Ab.w, a_r);
        a_u1 = __builtin_fmaf(ua,  Ba.x, a_u1);
        a_u1 = __builtin_fmaf(ub,  Bb.x, a_u1);
        a_u2 = __builtin_fmaf(ua,  Ba.y, a_u2);
        a_u2 = __builtin_fmaf(ub,  Bb.y, a_u2);
        a_u3 = __builtin_fmaf(ua,  Ba.z, a_u3);
        a_u3 = __builtin_fmaf(ub,  Bb.z, a_u3);
        a_u4 = __builtin_fmaf(rua, Ba.z, a_u4);
        a_u4 = __builtin_fmaf(rub, Bb.z, a_u4);
    }
    const float aD = a_u3 - 2.0f * a_u4;    // sum (u - 2ru) * w11^2 w2 = sum t*u*w11^2*w2

    red[wv][lane] = make_float4(a_r, a_u1, a_u2, aD);
    __syncthreads();
    if (tid < 64) {
        float4 s = red[0][tid];
        #pragma unroll
        for (int w = 1; w < 16; ++w) {
            const float4 o = red[w][tid];
            s.x += o.x; s.y += o.y; s.z += o.z; s.w += o.w;
        }
        // f = sum w2*(1-2r) + b2 ; df_dt = 4*sum u*w10*w2 ; df_dx = 4*sum u*w11*w2
        // df_dxdx = -8 * sum t*u*w11^2*w2
        const float f   = sfb - 2.0f * s.x;
        const float ft  = 4.0f * s.y;
        const float fx  = 4.0f * s.z;
        const float fxx = -8.0f * s.w;
        gridout[bid * 64 + tid] = make_float4(f, ft, fx, fxx);
    }
}

// ===== K2: bicubic interp + wave-cooperative direct fallback for outliers =====
__global__ __launch_bounds__(256) void interp_kernel(const float2* __restrict__ x2,
                                                     const float4* __restrict__ grid,
                                                     const float* __restrict__ W1,
                                                     const float* __restrict__ b1,
                                                     const float* __restrict__ w2,
                                                     const float* __restrict__ b2p,
                                                     float* __restrict__ out) {
    const int i = blockIdx.x * 256 + threadIdx.x;
    const float2 xv = x2[i];

    float u = (xv.x - GLO) * GINV;
    float v = (xv.y - GLO) * GINV;
    u = fminf(fmaxf(u, 0.0f), (float)(G - 1) - 1e-3f);
    v = fminf(fmaxf(v, 0.0f), (float)(G - 1) - 1e-3f);
    int iu = (int)u;  iu = iu > G - 2 ? G - 2 : iu;
    int iv = (int)v;  iv = iv > G - 2 ? G - 2 : iv;
    const float fu = u - (float)iu;
    const float fv = v - (float)iv;

    float wu[4], wv_[4];
    cr_w(fu, wu);
    cr_w(fv, wv_);

    const int ju0 = iu - 1 < 0 ? 0 : iu - 1;
    const int ju3 = iu + 2 > G - 1 ? G - 1 : iu + 2;
    const int jv0 = iv - 1 < 0 ? 0 : iv - 1;
    const int jv3 = iv + 2 > G - 1 ? G - 1 : iv + 2;
    const int rows[4] = { jv0 * G, iv * G, (iv + 1) * G, jv3 * G };

    float af = 0.f, at = 0.f, ax = 0.f, axx = 0.f;
    #pragma unroll
    for (int r = 0; r < 4; ++r) {
        const int base = rows[r];
        const float4 g0 = grid[base + ju0];
        const float4 g1 = grid[base + iu];
        const float4 g2 = grid[base + iu + 1];
        const float4 g3 = grid[base + ju3];
        const float rf  = wu[0] * g0.x + wu[1] * g1.x + wu[2] * g2.x + wu[3] * g3.x;
        const float rt  = wu[0] * g0.y + wu[1] * g1.y + wu[2] * g2.y + wu[3] * g3.y;
        const float rx  = wu[0] * g0.z + wu[1] * g1.z + wu[2] * g2.z + wu[3] * g3.z;
        const float rxx = wu[0] * g0.w + wu[1] * g1.w + wu[2] * g2.w + wu[3] * g3.w;
        af  = __builtin_fmaf(wv_[r], rf,  af);
        at  = __builtin_fmaf(wv_[r], rt,  at);
        ax  = __builtin_fmaf(wv_[r], rx,  ax);
        axx = __builtin_fmaf(wv_[r], rxx, axx);
    }

    // --- fallback: any lane outside the accurate table region gets an exact
    // direct evaluation, computed cooperatively by the whole wave. ---
    const bool outl = (fabsf(xv.x) > XMAX) || (fabsf(xv.y) > XMAX);
    unsigned long long mball = __ballot(outl);
    if (mball) {
        const int lane = threadIdx.x & 63;
        const float SC = 2.8853900817779268f;
        const float b2v = b2p[0];
        while (mball) {
            const int l = (int)__ffsll((unsigned long long)mball) - 1;
            mball &= mball - 1;
            const float fx0 = __shfl(xv.x, l, 64);
            const float fx1 = __shfl(xv.y, l, 64);
            float s_f = 0.f, s1 = 0.f, s2 = 0.f, s3 = 0.f, s4 = 0.f;
            for (int k = 0; k < 16; ++k) {
                const int h = lane * 16 + k;
                const float w10 = W1[2 * h], w11 = W1[2 * h + 1];
                const float b1h = b1[h], w2h = w2[h];
                float zs = SC * __builtin_fmaf(fx0, w10, __builtin_fmaf(fx1, w11, b1h));
                zs = fminf(zs, 40.0f);
                const float e = __builtin_amdgcn_exp2f(zs);
                const float r = __builtin_amdgcn_rcpf(e + 1.0f);
                const float t = __builtin_fmaf(-2.0f, r, 1.0f);
                const float uq = __builtin_fmaf(-r, r, r);
                const float ru = r * uq;
                const float c1 = w10 * w2h, c2 = w11 * w2h, c3 = w11 * c2;
                s_f += t * w2h;
                s1 = __builtin_fmaf(uq, c1, s1);
                s2 = __builtin_fmaf(uq, c2, s2);
                s3 = __builtin_fmaf(uq, c3, s3);
                s4 = __builtin_fmaf(ru, c3, s4);
            }
            #pragma unroll
            for (int m = 32; m >= 1; m >>= 1) {
                s_f += __shfl_xor(s_f, m, 64);
                s1  += __shfl_xor(s1,  m, 64);
                s2  += __shfl_xor(s2,  m, 64);
                s3  += __shfl_xor(s3,  m, 64);
                s4  += __shfl_xor(s4,  m, 64);
            }
            if (lane == l) {
                af  = s_f + b2v;
                at  = 4.0f * s1;
                ax  = 4.0f * s2;
                axx = -8.0f * (s3 - 2.0f * s4);
            }
        }
    }

    const float x1 = xv.y;
    const float pde = __builtin_fmaf(0.5f * x1, x1, at)
                    + 0.5f * axx
                    + 0.5f * x1 * ax
                    - 0.069444444444444445f * ax * ax;
    out[i] = af;
    out[PN + i] = pde;
}

extern "C" void kernel_launch(void* const* d_in, const int* in_sizes, int n_in,
                              void* d_out, int out_size, void* d_ws, size_t ws_size,
                              hipStream_t stream) {
    const float* x  = (const float*)d_in[0];
    const float* W1 = (const float*)d_in[1];
    const float* b1 = (const float*)d_in[2];
    const float* w2 = (const float*)d_in[3];
    const float* b2 = (const float*)d_in[4];
    float* out = (float*)d_out;
    float4* grid = (float4*)d_ws;      // G*G float4 = 256 KiB

    grid_eval_kernel<<<GPTS / 64, 1024, 0, stream>>>(W1, b1, w2, b2, grid);
    interp_kernel<<<PN / 256, 256, 0, stream>>>((const float2*)x, grid,
                                                W1, b1, w2, b2, out);
}